// Round 3
// baseline (440.041 us; speedup 1.0000x reference)
//
#include <hip/hip_runtime.h>

#define BB 8
#define NN 8700
#define CC 256
#define QQ 300
#define HH 8
#define DD 32
#define HIDN 1024
#define NSPLIT 12
#define KCHUNK 768

typedef unsigned short u16;
typedef __attribute__((ext_vector_type(8))) short short8;
typedef __attribute__((ext_vector_type(4))) float f32x4;

#define MFMA16(a, b, c) __builtin_amdgcn_mfma_f32_16x16x32_bf16((a), (b), (c), 0, 0, 0)

__device__ __forceinline__ u16 f2bu(float f) {
    unsigned int u = __builtin_bit_cast(unsigned int, f);
    u += 0x7fffu + ((u >> 16) & 1u);   // round-to-nearest-even
    return (u16)(u >> 16);
}
__device__ __forceinline__ u16 f2b_hw(float f) {
    unsigned int r;
    asm("v_cvt_pk_bf16_f32 %0, %1, %2" : "=v"(r) : "v"(f), "v"(0.f));
    return (u16)r;
}

// ---------------- weight prep: f32 [K][N] -> bf16 [N][K] (optionally scaled) ----------------
__global__ __launch_bounds__(256)
void wprep(const float* __restrict__ src, u16* __restrict__ dst, int K, int N, float scale)
{
    int e = blockIdx.x * 256 + threadIdx.x;
    if (e >= K * N) return;
    int n = e / K, kk = e - n * K;
    dst[e] = f2bu(src[(size_t)kk * N + n] * scale);
}

// ---------------- LN1 + context-token output ----------------
__global__ __launch_bounds__(256)
void ln1_k(const float* __restrict__ x, const float* __restrict__ w,
           const float* __restrict__ bv, const float* __restrict__ g1,
           u16* __restrict__ xn, float* __restrict__ out)
{
    int row = blockIdx.x * 4 + (threadIdx.x >> 6);
    int l = threadIdx.x & 63;
    size_t base = (size_t)row * CC + l * 4;
    float4 xv = *reinterpret_cast<const float4*>(x + base);
    float s  = xv.x + xv.y + xv.z + xv.w;
    float s2 = xv.x * xv.x + xv.y * xv.y + xv.z * xv.z + xv.w * xv.w;
#pragma unroll
    for (int m = 1; m < 64; m <<= 1) {
        s  += __shfl_xor(s,  m, 64);
        s2 += __shfl_xor(s2, m, 64);
    }
    float mean = s * (1.0f / CC);
    float rs = rsqrtf(s2 * (1.0f / CC) - mean * mean + 1e-5f);
    float4 wv = *reinterpret_cast<const float4*>(w  + l * 4);
    float4 bb = *reinterpret_cast<const float4*>(bv + l * 4);
    float n0 = (xv.x - mean) * rs * wv.x + bb.x;
    float n1 = (xv.y - mean) * rs * wv.y + bb.y;
    float n2 = (xv.z - mean) * rs * wv.z + bb.z;
    float n3 = (xv.w - mean) * rs * wv.w + bb.w;
    ushort4 u; u.x = f2bu(n0); u.y = f2bu(n1); u.z = f2bu(n2); u.w = f2bu(n3);
    *reinterpret_cast<ushort4*>(xn + base) = u;
    int n = row % NN;
    if (n >= QQ) {
        float4 gv = *reinterpret_cast<const float4*>(g1 + l * 4);
        float4 o;
        o.x = 2.0f * (xv.x + gv.x * n0);
        o.y = 2.0f * (xv.y + gv.y * n1);
        o.z = 2.0f * (xv.z + gv.z * n2);
        o.w = 2.0f * (xv.w + gv.w * n3);
        *reinterpret_cast<float4*>(out + base) = o;
    }
}

// ---------------- residual + LN2 for query tokens ----------------
__global__ __launch_bounds__(256)
void ln2_k(const float* __restrict__ x, const float* __restrict__ pd,
           const float* __restrict__ g1, const float* __restrict__ w,
           const float* __restrict__ bv, float* __restrict__ xqf, u16* __restrict__ xqb)
{
    int r = blockIdx.x * 4 + (threadIdx.x >> 6);
    int l = threadIdx.x & 63;
    int b = r / QQ, n = r - b * QQ;
    size_t xoff = ((size_t)b * NN + n) * CC + l * 4;
    size_t roff = (size_t)r * CC + l * 4;
    float4 xv = *reinterpret_cast<const float4*>(x + xoff);
    float4 pv = *reinterpret_cast<const float4*>(pd + roff);
    float4 gv = *reinterpret_cast<const float4*>(g1 + l * 4);
    float x0 = xv.x + gv.x * pv.x;
    float x1 = xv.y + gv.y * pv.y;
    float x2 = xv.z + gv.z * pv.z;
    float x3 = xv.w + gv.w * pv.w;
    float s  = x0 + x1 + x2 + x3;
    float s2 = x0 * x0 + x1 * x1 + x2 * x2 + x3 * x3;
#pragma unroll
    for (int m = 1; m < 64; m <<= 1) {
        s  += __shfl_xor(s,  m, 64);
        s2 += __shfl_xor(s2, m, 64);
    }
    float mean = s * (1.0f / CC);
    float rs = rsqrtf(s2 * (1.0f / CC) - mean * mean + 1e-5f);
    float4 wv = *reinterpret_cast<const float4*>(w  + l * 4);
    float4 bb = *reinterpret_cast<const float4*>(bv + l * 4);
    float n0 = (x0 - mean) * rs * wv.x + bb.x;
    float n1 = (x1 - mean) * rs * wv.y + bb.y;
    float n2 = (x2 - mean) * rs * wv.z + bb.z;
    float n3 = (x3 - mean) * rs * wv.w + bb.w;
    float4 o; o.x = n0; o.y = n1; o.z = n2; o.w = n3;
    *reinterpret_cast<float4*>(xqf + roff) = o;
    ushort4 u; u.x = f2bu(n0); u.y = f2bu(n1); u.z = f2bu(n2); u.w = f2bu(n3);
    *reinterpret_cast<ushort4*>(xqb + roff) = u;
}

// ---------------- generic 4-wave MFMA GEMM ----------------
// EPI: 0 = bf16 store (dual dest: col<256 -> Cb, else Cb2), 1 = GELU->bf16,
//      2 = f32 store, 3 = out = base + gvec*acc -> d_out (row remap)
template<int EPI>
__global__ __launch_bounds__(256)
void gemm_k(const u16* __restrict__ A, const u16* __restrict__ WT,
            u16* __restrict__ Cb, u16* __restrict__ Cb2, float* __restrict__ Cf,
            const float* __restrict__ basep, const float* __restrict__ gvec,
            float* __restrict__ outp,
            int M, int K, int ldC, int rpb, int bstr)
{
    const int w = threadIdx.x >> 6, l = threadIdx.x & 63;
    const int l15 = l & 15, kg = l >> 4;
    const int rowbase = blockIdx.x * 64;
    const int colbase = blockIdx.y * 256 + w * 64;
    const short8 z8 = {0, 0, 0, 0, 0, 0, 0, 0};
    const f32x4 fz = {0.f, 0.f, 0.f, 0.f};

    const u16* ap[4]; bool av[4];
#pragma unroll
    for (int mi = 0; mi < 4; mi++) {
        int r = rowbase + mi * 16 + l15;
        av[mi] = (r < M);
        int rr = av[mi] ? r : 0;
        size_t ar = (size_t)(rr / rpb) * bstr + (rr % rpb);
        ap[mi] = A + ar * K + kg * 8;
    }
    const u16* bp[4];
#pragma unroll
    for (int ni = 0; ni < 4; ni++) {
        int col = colbase + ni * 16 + l15;
        bp[ni] = WT + (size_t)col * K + kg * 8;
    }
    f32x4 acc[4][4];
#pragma unroll
    for (int mi = 0; mi < 4; mi++)
#pragma unroll
        for (int ni = 0; ni < 4; ni++) acc[mi][ni] = fz;

    for (int ks = 0; ks < K; ks += 32) {
        short8 a[4], bfr[4];
#pragma unroll
        for (int mi = 0; mi < 4; mi++)
            a[mi] = av[mi] ? *reinterpret_cast<const short8*>(ap[mi] + ks) : z8;
#pragma unroll
        for (int ni = 0; ni < 4; ni++)
            bfr[ni] = *reinterpret_cast<const short8*>(bp[ni] + ks);
#pragma unroll
        for (int mi = 0; mi < 4; mi++)
#pragma unroll
            for (int ni = 0; ni < 4; ni++)
                acc[mi][ni] = MFMA16(a[mi], bfr[ni], acc[mi][ni]);
    }
#pragma unroll
    for (int mi = 0; mi < 4; mi++) {
#pragma unroll
        for (int j = 0; j < 4; j++) {
            int r = rowbase + mi * 16 + kg * 4 + j;
            if (r >= M) continue;
#pragma unroll
            for (int ni = 0; ni < 4; ni++) {
                int col = colbase + ni * 16 + l15;
                float v = acc[mi][ni][j];
                if (EPI == 0) {
                    if (col < CC) Cb[(size_t)r * ldC + col] = f2bu(v);
                    else          Cb2[(size_t)r * ldC + (col - CC)] = f2bu(v);
                } else if (EPI == 1) {
                    float gl = 0.5f * v * (1.0f + erff(v * 0.70710678118654752f));
                    Cb[(size_t)r * ldC + col] = f2bu(gl);
                } else if (EPI == 2) {
                    Cf[(size_t)r * ldC + col] = v;
                } else {
                    float res = basep[(size_t)r * CC + col] + gvec[col] * v;
                    size_t orow = (size_t)(r / QQ) * NN + (r % QQ);
                    outp[orow * CC + col] = res;
                }
            }
        }
    }
}

// ---------------- flash attention, key-split (64-key tiles) ----------------
__global__ __launch_bounds__(256)
void attn_k(const u16* __restrict__ qm, const u16* __restrict__ km,
            const u16* __restrict__ vm, float* __restrict__ Op,
            float* __restrict__ mp, float* __restrict__ lp)
{
    __shared__ u16 vt[2][32 * 64];     // [d][key], XOR-swizzled
    __shared__ u16 plds[4][80 * 64];   // per-wave P, XOR-swizzled

    const int split = blockIdx.x % NSPLIT;
    const int bh = blockIdx.x / NSPLIT;
    const int b = bh >> 3, h = bh & 7;
    const int tid = threadIdx.x;
    const int w = tid >> 6, l = tid & 63;
    const int l15 = l & 15, kg = l >> 4;
    const int n0base = split * KCHUNK;
    const int nend = (n0base + KCHUNK < NN) ? n0base + KCHUNK : NN;
    const int nt = (nend - n0base + 63) >> 6;

    const short8 z8 = {0, 0, 0, 0, 0, 0, 0, 0};
    const f32x4 fz = {0.f, 0.f, 0.f, 0.f};

    const u16* kbase = km + (size_t)b * NN * CC + h * DD;
    const u16* vbase = vm + (size_t)b * NN * CC + h * DD;
    const int vkey = tid & 63, vd0 = (tid >> 6) * 8;

    short8 qf[5];
#pragma unroll
    for (int mf = 0; mf < 5; mf++) {
        int qrow = w * 80 + mf * 16 + l15;
        int qc = qrow < QQ ? qrow : 0;
        short8 v = *reinterpret_cast<const short8*>(qm + ((size_t)(b * QQ + qc) * CC + h * DD + kg * 8));
        qf[mf] = (qrow < QQ) ? v : z8;
    }

    f32x4 o[5][2]; float mrun[5][4], lpart[5][4];
#pragma unroll
    for (int mf = 0; mf < 5; mf++) {
        o[mf][0] = fz; o[mf][1] = fz;
#pragma unroll
        for (int j = 0; j < 4; j++) { mrun[mf][j] = -1e30f; lpart[mf][j] = 0.f; }
    }

    // prologue loads (tile 0)
    short8 kf[4]; short8 vr;
#pragma unroll
    for (int kb = 0; kb < 4; kb++)
        kf[kb] = *reinterpret_cast<const short8*>(kbase + (size_t)(n0base + kb * 16 + l15) * CC + kg * 8);
    { int n = n0base + vkey;
      vr = (n < NN) ? *reinterpret_cast<const short8*>(vbase + (size_t)n * CC + vd0) : z8; }

    int n0 = n0base;
    for (int t = 0; t < nt; ++t, n0 += 64) {
        // stage V(t) -> vt[t&1], transposed + swizzled
        char* vtb = (char*)vt[t & 1];
#pragma unroll
        for (int i = 0; i < 8; i++) {
            int row = vd0 + i;
            int byteo = ((row << 7) + (vkey << 1)) ^ ((row & 7) << 4);
            *reinterpret_cast<u16*>(vtb + byteo) = (u16)vr[i];
        }
        __syncthreads();

        const bool tail = (n0 + 64 > NN);
        char* pl = (char*)plds[w];

#pragma unroll
        for (int mf = 0; mf < 5; mf++) {
            f32x4 s[4];
#pragma unroll
            for (int kb = 0; kb < 4; kb++)
                s[kb] = MFMA16(qf[mf], kf[kb], fz);
            if (tail) {
#pragma unroll
                for (int kb = 0; kb < 4; kb++) {
                    bool inv = (n0 + kb * 16 + l15) >= NN;
                    if (inv)
#pragma unroll
                        for (int j = 0; j < 4; j++) s[kb][j] = -1e30f;
                }
            }
            float tm[4];
#pragma unroll
            for (int j = 0; j < 4; j++)
                tm[j] = fmaxf(fmaxf(s[0][j], s[1][j]), fmaxf(s[2][j], s[3][j]));
#pragma unroll
            for (int msk = 1; msk < 16; msk <<= 1)
#pragma unroll
                for (int j = 0; j < 4; j++) tm[j] = fmaxf(tm[j], __shfl_xor(tm[j], msk, 64));
            bool grow = false;
#pragma unroll
            for (int j = 0; j < 4; j++) grow = grow || (tm[j] > mrun[mf][j] + 8.f);
            if (__any(grow)) {
#pragma unroll
                for (int j = 0; j < 4; j++) {
                    float mn = fmaxf(mrun[mf][j], tm[j]);
                    float al = exp2f(mrun[mf][j] - mn);
                    mrun[mf][j] = mn;
                    lpart[mf][j] *= al;
                    o[mf][0][j] *= al;
                    o[mf][1][j] *= al;
                }
            }
#pragma unroll
            for (int j = 0; j < 4; j++) {
                int row = mf * 16 + kg * 4 + j;
                float psum = 0.f;
#pragma unroll
                for (int kb = 0; kb < 4; kb++) {
                    float pq = exp2f(s[kb][j] - mrun[mf][j]);
                    psum += pq;
                    // write swizzle == read swizzle: XOR applied AFTER the full (row,col) offset
                    int byteo = ((row << 7) + ((kb * 16 + l15) << 1)) ^ ((row & 7) << 4);
                    *reinterpret_cast<u16*>(pl + byteo) = f2b_hw(pq);
                }
                lpart[mf][j] += psum;
            }
        }

        // prefetch next tile (latency hidden under PV)
        { int n0n = (t + 1 < nt) ? n0 + 64 : n0base;
#pragma unroll
          for (int kb = 0; kb < 4; kb++)
              kf[kb] = *reinterpret_cast<const short8*>(kbase + (size_t)(n0n + kb * 16 + l15) * CC + kg * 8);
          int n = n0n + vkey;
          vr = (n < NN) ? *reinterpret_cast<const short8*>(vbase + (size_t)n * CC + vd0) : z8; }

        // PV
        short8 vb[2][2];
#pragma unroll
        for (int ks = 0; ks < 2; ks++)
#pragma unroll
            for (int db = 0; db < 2; db++) {
                int row = db * 16 + l15;
                int byteo = ((row << 7) + ks * 64 + kg * 16) ^ ((row & 7) << 4);
                vb[ks][db] = *reinterpret_cast<const short8*>(vtb + byteo);
            }
#pragma unroll
        for (int mf = 0; mf < 5; mf++) {
            int arow = mf * 16 + l15;
#pragma unroll
            for (int ks = 0; ks < 2; ks++) {
                int abyte = ((arow << 7) + ks * 64 + kg * 16) ^ ((arow & 7) << 4);
                short8 pa = *reinterpret_cast<const short8*>(pl + abyte);
                o[mf][0] = MFMA16(pa, vb[ks][0], o[mf][0]);
                o[mf][1] = MFMA16(pa, vb[ks][1], o[mf][1]);
            }
        }
    }

    // final lane-group reduce of the denominator
#pragma unroll
    for (int mf = 0; mf < 5; mf++)
#pragma unroll
        for (int j = 0; j < 4; j++)
#pragma unroll
            for (int msk = 1; msk < 16; msk <<= 1)
                lpart[mf][j] += __shfl_xor(lpart[mf][j], msk, 64);

    size_t pb = (size_t)(split * 64 + bh) * QQ;
#pragma unroll
    for (int mf = 0; mf < 5; mf++) {
#pragma unroll
        for (int j = 0; j < 4; j++) {
            int qrow = w * 80 + mf * 16 + kg * 4 + j;
            if (qrow >= QQ) continue;
            size_t pr = pb + qrow;
            if (l15 == 0) { mp[pr] = mrun[mf][j]; lp[pr] = lpart[mf][j]; }
            Op[pr * DD + l15]      = o[mf][0][j];
            Op[pr * DD + 16 + l15] = o[mf][1][j];
        }
    }
}

// ---------------- combine split partials ----------------
__global__ __launch_bounds__(256)
void comb_k(const float* __restrict__ Op, const float* __restrict__ mp,
            const float* __restrict__ lp, u16* __restrict__ ao)
{
    int g = blockIdx.x * 256 + threadIdx.x;    // 2400 rows * 8 threads
    int d4 = (g & 7) * 4;
    int row = g >> 3;
    int bh = row / QQ, qq = row - bh * QQ;
    int b = bh >> 3, h = bh & 7;
    float ms[NSPLIT], M = -1e30f;
#pragma unroll
    for (int s = 0; s < NSPLIT; s++) {
        ms[s] = mp[(size_t)(s * 64 + bh) * QQ + qq];
        M = fmaxf(M, ms[s]);
    }
    float L = 0.f, a0 = 0.f, a1 = 0.f, a2 = 0.f, a3 = 0.f;
#pragma unroll
    for (int s = 0; s < NSPLIT; s++) {
        size_t pr = (size_t)(s * 64 + bh) * QQ + qq;
        float e = exp2f(ms[s] - M);
        L += lp[pr] * e;
        float4 ov = *reinterpret_cast<const float4*>(Op + pr * DD + d4);
        a0 += e * ov.x; a1 += e * ov.y; a2 += e * ov.z; a3 += e * ov.w;
    }
    float inv = 1.0f / L;
    ushort4 u;
    u.x = f2bu(a0 * inv); u.y = f2bu(a1 * inv); u.z = f2bu(a2 * inv); u.w = f2bu(a3 * inv);
    *reinterpret_cast<ushort4*>(ao + ((size_t)(b * QQ + qq) * CC + h * DD + d4)) = u;
}

// ---------------- launch ----------------
extern "C" void kernel_launch(void* const* d_in, const int* in_sizes, int n_in,
                              void* d_out, int out_size, void* d_ws, size_t ws_size,
                              hipStream_t stream)
{
    (void)in_sizes; (void)n_in; (void)out_size; (void)ws_size;
    const float* x    = (const float*)d_in[0];
    const float* Wq   = (const float*)d_in[1];
    const float* Wk   = (const float*)d_in[2];
    const float* Wv   = (const float*)d_in[3];
    const float* Wp   = (const float*)d_in[4];
    const float* W1   = (const float*)d_in[5];
    const float* W2   = (const float*)d_in[6];
    const float* ln1w = (const float*)d_in[7];
    const float* ln1b = (const float*)d_in[8];
    const float* ln2w = (const float*)d_in[9];
    const float* ln2b = (const float*)d_in[10];
    const float* g1   = (const float*)d_in[11];
    const float* g2   = (const float*)d_in[12];
    float* out = (float*)d_out;

    char* p = (char*)d_ws;
    auto alloc = [&](size_t bytes) { char* r = p; p += (bytes + 255) & ~(size_t)255; return r; };

    const size_t MKV = (size_t)BB * NN;        // 69600
    const size_t MQ  = (size_t)BB * QQ;        // 2400

    u16* WqT  = (u16*)alloc((size_t)CC * CC * 2);
    u16* WkvT = (u16*)alloc((size_t)CC * CC * 2 * 2);   // K cols then V cols, contiguous
    u16* WpT  = (u16*)alloc((size_t)CC * CC * 2);
    u16* W1T  = (u16*)alloc((size_t)CC * HIDN * 2);
    u16* W2T  = (u16*)alloc((size_t)HIDN * CC * 2);
    u16* xn   = (u16*)alloc(MKV * CC * 2);
    u16* kbf  = (u16*)alloc(MKV * CC * 2);
    u16* vbf  = (u16*)alloc(MKV * CC * 2);
    u16* qbf  = (u16*)alloc(MQ * CC * 2);
    u16* aob  = (u16*)alloc(MQ * CC * 2);
    u16* xqb  = (u16*)alloc(MQ * CC * 2);
    u16* h1   = (u16*)alloc(MQ * HIDN * 2);
    float* pd  = (float*)alloc(MQ * CC * 4);
    float* xqf = (float*)alloc(MQ * CC * 4);
    float* Op  = (float*)alloc((size_t)NSPLIT * 64 * QQ * DD * 4);
    float* mp  = (float*)alloc((size_t)NSPLIT * 64 * QQ * 4);
    float* lp  = (float*)alloc((size_t)NSPLIT * 64 * QQ * 4);

    // D^-0.5 * log2(e): scores land in log2 domain -> exp2 everywhere
    const float qscale = 0.17677669529663687f * 1.4426950408889634f;

    wprep<<<(CC * CC + 255) / 256, 256, 0, stream>>>(Wq, WqT, CC, CC, qscale);
    wprep<<<(CC * CC + 255) / 256, 256, 0, stream>>>(Wk, WkvT, CC, CC, 1.0f);
    wprep<<<(CC * CC + 255) / 256, 256, 0, stream>>>(Wv, WkvT + (size_t)CC * CC, CC, CC, 1.0f);
    wprep<<<(CC * CC + 255) / 256, 256, 0, stream>>>(Wp, WpT, CC, CC, 1.0f);
    wprep<<<(CC * HIDN + 255) / 256, 256, 0, stream>>>(W1, W1T, CC, HIDN, 1.0f);
    wprep<<<(HIDN * CC + 255) / 256, 256, 0, stream>>>(W2, W2T, HIDN, CC, 1.0f);

    // LN1 + context output
    ln1_k<<<(int)(MKV / 4), 256, 0, stream>>>(x, ln1w, ln1b, g1, xn, out);

    // fused K+V projection (one pass over xn), then Q
    gemm_k<0><<<dim3(1088, 2), 256, 0, stream>>>(xn, WkvT, kbf, vbf, nullptr, nullptr, nullptr, nullptr,
                                                 (int)MKV, CC, CC, (int)MKV, 0);
    gemm_k<0><<<dim3(38, 1), 256, 0, stream>>>(xn, WqT, qbf, nullptr, nullptr, nullptr, nullptr, nullptr,
                                               (int)MQ, CC, CC, QQ, NN);

    // attention (key-split flash) + combine
    attn_k<<<64 * NSPLIT, 256, 0, stream>>>(qbf, kbf, vbf, Op, mp, lp);
    comb_k<<<(int)(MQ * 8 / 256), 256, 0, stream>>>(Op, mp, lp, aob);

    // proj -> f32
    gemm_k<2><<<dim3(38, 1), 256, 0, stream>>>(aob, WpT, nullptr, nullptr, pd, nullptr, nullptr, nullptr,
                                               (int)MQ, CC, CC, (int)MQ, 0);
    // residual + LN2
    ln2_k<<<(int)(MQ / 4), 256, 0, stream>>>(x, pd, g1, ln2w, ln2b, xqf, xqb);

    // MLP
    gemm_k<1><<<dim3(38, 4), 256, 0, stream>>>(xqb, W1T, h1, nullptr, nullptr, nullptr, nullptr, nullptr,
                                               (int)MQ, CC, HIDN, (int)MQ, 0);
    gemm_k<3><<<dim3(38, 1), 256, 0, stream>>>(h1, W2T, nullptr, nullptr, nullptr, xqf, g2, out,
                                               (int)MQ, HIDN, CC, (int)MQ, 0);
}

// Round 4
// 299.662 us; speedup vs baseline: 1.4685x; 1.4685x over previous
//
#include <hip/hip_runtime.h>

#define BB 8
#define NN 8700
#define CC 256
#define QQ 300
#define HH 8
#define DD 32
#define HIDN 1024
#define NSPLIT 8
#define KCHUNK 1088

typedef unsigned short u16;
typedef __attribute__((ext_vector_type(8))) short short8;
typedef __attribute__((ext_vector_type(4))) float f32x4;

#define MFMA16(a, b, c) __builtin_amdgcn_mfma_f32_16x16x32_bf16((a), (b), (c), 0, 0, 0)

__device__ __forceinline__ u16 f2bu(float f) {
    unsigned int u = __builtin_bit_cast(unsigned int, f);
    u += 0x7fffu + ((u >> 16) & 1u);   // round-to-nearest-even
    return (u16)(u >> 16);
}
__device__ __forceinline__ unsigned int cvtpk(float lo, float hi) {
    unsigned int r;
    asm("v_cvt_pk_bf16_f32 %0, %1, %2" : "=v"(r) : "v"(lo), "v"(hi));
    return r;
}

// ---------------- weight prep: f32 [K][N] -> bf16 [N][K] (optionally scaled) ----------------
__global__ __launch_bounds__(256)
void wprep(const float* __restrict__ src, u16* __restrict__ dst, int K, int N, float scale)
{
    int e = blockIdx.x * 256 + threadIdx.x;
    if (e >= K * N) return;
    int n = e / K, kk = e - n * K;
    dst[e] = f2bu(src[(size_t)kk * N + n] * scale);
}

// ---------------- LN1 + context-token output ----------------
__global__ __launch_bounds__(256)
void ln1_k(const float* __restrict__ x, const float* __restrict__ w,
           const float* __restrict__ bv, const float* __restrict__ g1,
           u16* __restrict__ xn, float* __restrict__ out)
{
    int row = blockIdx.x * 4 + (threadIdx.x >> 6);
    int l = threadIdx.x & 63;
    size_t base = (size_t)row * CC + l * 4;
    float4 xv = *reinterpret_cast<const float4*>(x + base);
    float s  = xv.x + xv.y + xv.z + xv.w;
    float s2 = xv.x * xv.x + xv.y * xv.y + xv.z * xv.z + xv.w * xv.w;
#pragma unroll
    for (int m = 1; m < 64; m <<= 1) {
        s  += __shfl_xor(s,  m, 64);
        s2 += __shfl_xor(s2, m, 64);
    }
    float mean = s * (1.0f / CC);
    float rs = rsqrtf(s2 * (1.0f / CC) - mean * mean + 1e-5f);
    float4 wv = *reinterpret_cast<const float4*>(w  + l * 4);
    float4 bb = *reinterpret_cast<const float4*>(bv + l * 4);
    float n0 = (xv.x - mean) * rs * wv.x + bb.x;
    float n1 = (xv.y - mean) * rs * wv.y + bb.y;
    float n2 = (xv.z - mean) * rs * wv.z + bb.z;
    float n3 = (xv.w - mean) * rs * wv.w + bb.w;
    ushort4 u; u.x = f2bu(n0); u.y = f2bu(n1); u.z = f2bu(n2); u.w = f2bu(n3);
    *reinterpret_cast<ushort4*>(xn + base) = u;
    int n = row % NN;
    if (n >= QQ) {
        float4 gv = *reinterpret_cast<const float4*>(g1 + l * 4);
        float4 o;
        o.x = 2.0f * (xv.x + gv.x * n0);
        o.y = 2.0f * (xv.y + gv.y * n1);
        o.z = 2.0f * (xv.z + gv.z * n2);
        o.w = 2.0f * (xv.w + gv.w * n3);
        *reinterpret_cast<float4*>(out + base) = o;
    }
}

// ---------------- residual + LN2 for query tokens ----------------
__global__ __launch_bounds__(256)
void ln2_k(const float* __restrict__ x, const float* __restrict__ pd,
           const float* __restrict__ g1, const float* __restrict__ w,
           const float* __restrict__ bv, float* __restrict__ xqf, u16* __restrict__ xqb)
{
    int r = blockIdx.x * 4 + (threadIdx.x >> 6);
    int l = threadIdx.x & 63;
    int b = r / QQ, n = r - b * QQ;
    size_t xoff = ((size_t)b * NN + n) * CC + l * 4;
    size_t roff = (size_t)r * CC + l * 4;
    float4 xv = *reinterpret_cast<const float4*>(x + xoff);
    float4 pv = *reinterpret_cast<const float4*>(pd + roff);
    float4 gv = *reinterpret_cast<const float4*>(g1 + l * 4);
    float x0 = xv.x + gv.x * pv.x;
    float x1 = xv.y + gv.y * pv.y;
    float x2 = xv.z + gv.z * pv.z;
    float x3 = xv.w + gv.w * pv.w;
    float s  = x0 + x1 + x2 + x3;
    float s2 = x0 * x0 + x1 * x1 + x2 * x2 + x3 * x3;
#pragma unroll
    for (int m = 1; m < 64; m <<= 1) {
        s  += __shfl_xor(s,  m, 64);
        s2 += __shfl_xor(s2, m, 64);
    }
    float mean = s * (1.0f / CC);
    float rs = rsqrtf(s2 * (1.0f / CC) - mean * mean + 1e-5f);
    float4 wv = *reinterpret_cast<const float4*>(w  + l * 4);
    float4 bb = *reinterpret_cast<const float4*>(bv + l * 4);
    float n0 = (x0 - mean) * rs * wv.x + bb.x;
    float n1 = (x1 - mean) * rs * wv.y + bb.y;
    float n2 = (x2 - mean) * rs * wv.z + bb.z;
    float n3 = (x3 - mean) * rs * wv.w + bb.w;
    float4 o; o.x = n0; o.y = n1; o.z = n2; o.w = n3;
    *reinterpret_cast<float4*>(xqf + roff) = o;
    ushort4 u; u.x = f2bu(n0); u.y = f2bu(n1); u.z = f2bu(n2); u.w = f2bu(n3);
    *reinterpret_cast<ushort4*>(xqb + roff) = u;
}

// ---------------- generic 4-wave MFMA GEMM ----------------
// EPI: 0 = bf16 store (dual dest: col<256 -> Cb, else Cb2), 1 = GELU->bf16,
//      2 = f32 store, 3 = out = base + gvec*acc -> d_out (row remap)
template<int EPI>
__global__ __launch_bounds__(256)
void gemm_k(const u16* __restrict__ A, const u16* __restrict__ WT,
            u16* __restrict__ Cb, u16* __restrict__ Cb2, float* __restrict__ Cf,
            const float* __restrict__ basep, const float* __restrict__ gvec,
            float* __restrict__ outp,
            int M, int K, int ldC, int rpb, int bstr)
{
    const int w = threadIdx.x >> 6, l = threadIdx.x & 63;
    const int l15 = l & 15, kg = l >> 4;
    const int rowbase = blockIdx.x * 64;
    const int colbase = blockIdx.y * 256 + w * 64;
    const short8 z8 = {0, 0, 0, 0, 0, 0, 0, 0};
    const f32x4 fz = {0.f, 0.f, 0.f, 0.f};

    const u16* ap[4]; bool av[4];
#pragma unroll
    for (int mi = 0; mi < 4; mi++) {
        int r = rowbase + mi * 16 + l15;
        av[mi] = (r < M);
        int rr = av[mi] ? r : 0;
        size_t ar = (size_t)(rr / rpb) * bstr + (rr % rpb);
        ap[mi] = A + ar * K + kg * 8;
    }
    const u16* bp[4];
#pragma unroll
    for (int ni = 0; ni < 4; ni++) {
        int col = colbase + ni * 16 + l15;
        bp[ni] = WT + (size_t)col * K + kg * 8;
    }
    f32x4 acc[4][4];
#pragma unroll
    for (int mi = 0; mi < 4; mi++)
#pragma unroll
        for (int ni = 0; ni < 4; ni++) acc[mi][ni] = fz;

    for (int ks = 0; ks < K; ks += 32) {
        short8 a[4], bfr[4];
#pragma unroll
        for (int mi = 0; mi < 4; mi++)
            a[mi] = av[mi] ? *reinterpret_cast<const short8*>(ap[mi] + ks) : z8;
#pragma unroll
        for (int ni = 0; ni < 4; ni++)
            bfr[ni] = *reinterpret_cast<const short8*>(bp[ni] + ks);
#pragma unroll
        for (int mi = 0; mi < 4; mi++)
#pragma unroll
            for (int ni = 0; ni < 4; ni++)
                acc[mi][ni] = MFMA16(a[mi], bfr[ni], acc[mi][ni]);
    }
#pragma unroll
    for (int mi = 0; mi < 4; mi++) {
#pragma unroll
        for (int j = 0; j < 4; j++) {
            int r = rowbase + mi * 16 + kg * 4 + j;
            if (r >= M) continue;
#pragma unroll
            for (int ni = 0; ni < 4; ni++) {
                int col = colbase + ni * 16 + l15;
                float v = acc[mi][ni][j];
                if (EPI == 0) {
                    if (col < CC) Cb[(size_t)r * ldC + col] = f2bu(v);
                    else          Cb2[(size_t)r * ldC + (col - CC)] = f2bu(v);
                } else if (EPI == 1) {
                    float gl = 0.5f * v * (1.0f + erff(v * 0.70710678118654752f));
                    Cb[(size_t)r * ldC + col] = f2bu(gl);
                } else if (EPI == 2) {
                    Cf[(size_t)r * ldC + col] = v;
                } else {
                    float res = basep[(size_t)r * CC + col] + gvec[col] * v;
                    size_t orow = (size_t)(r / QQ) * NN + (r % QQ);
                    outp[orow * CC + col] = res;
                }
            }
        }
    }
}

// ---------------- flash attention: swapped QK^T, in-register P exchange ----------------
// grid: 512 = split*64 + h*8 + b  (same (split,b) heads share an XCD L2)
__global__ __launch_bounds__(256)
void attn_k(const u16* __restrict__ qm, const u16* __restrict__ km,
            const u16* __restrict__ vm, float* __restrict__ Op,
            float* __restrict__ mp, float* __restrict__ lp)
{
    __shared__ u16 vt[2][32 * 64];   // [d][key], XOR-swizzled

    const int bx = blockIdx.x;
    const int split = bx >> 6;
    const int rem = bx & 63;
    const int h = rem >> 3, b = rem & 7;
    const int bh = b * HH + h;
    const int tid = threadIdx.x;
    const int w = tid >> 6, l = tid & 63;
    const int l15 = l & 15, kg = l >> 4;
    const int n0base = split * KCHUNK;
    const int nend = (n0base + KCHUNK < NN) ? n0base + KCHUNK : NN;
    const int nt = (nend - n0base + 63) >> 6;

    const f32x4 fz = {0.f, 0.f, 0.f, 0.f};

    const u16* kbase = km + (size_t)b * NN * CC + h * DD;
    const u16* vbase = vm + (size_t)b * NN * CC + h * DD;
    const int vkey = tid & 63, vd0 = (tid >> 6) * 8;

    // Q as B-fragments: lane reads Q row (w*80 + qf*16 + l15), 16B at d=kg*8
    short8 qfr[5];
#pragma unroll
    for (int qf = 0; qf < 5; qf++) {
        int qrow = w * 80 + qf * 16 + l15;
        int qc = qrow < QQ ? qrow : 0;
        qfr[qf] = *reinterpret_cast<const short8*>(qm + ((size_t)(b * QQ + qc) * CC + h * DD + kg * 8));
    }

    f32x4 o[2][5]; float mrun[5], lpart[5];
#pragma unroll
    for (int qf = 0; qf < 5; qf++) {
        o[0][qf] = fz; o[1][qf] = fz; mrun[qf] = -1e30f; lpart[qf] = 0.f;
    }

    // exchange lane mapping (constant across tiles)
    const int srcA = l15 + ((kg & 1) << 5);
    const int srcB = srcA + 16;
    const bool selhi = (kg & 2) != 0;

    // prologue: load K/V tile 0
    short8 kf[4], vr;
#pragma unroll
    for (int kb = 0; kb < 4; kb++) {
        int n = n0base + kb * 16 + l15; if (n > NN - 1) n = NN - 1;
        kf[kb] = *reinterpret_cast<const short8*>(kbase + (size_t)n * CC + kg * 8);
    }
    { int n = n0base + vkey; if (n > NN - 1) n = NN - 1;
      vr = *reinterpret_cast<const short8*>(vbase + (size_t)n * CC + vd0); }

    int n0 = n0base;
    for (int t = 0; t < nt; ++t, n0 += 64) {
        // stage V(t) -> vt[t&1], transposed + swizzled
        char* vtb = (char*)vt[t & 1];
#pragma unroll
        for (int i = 0; i < 8; i++) {
            int row = vd0 + i;
            int byteo = ((row << 7) + (vkey << 1)) ^ ((row & 7) << 4);
            *reinterpret_cast<u16*>(vtb + byteo) = (u16)vr[i];
        }
        __syncthreads();

        // issue next-tile prefetch early: latency hides under the whole tile body
        short8 kfn[4], vrn;
        { int n0n = (t + 1 < nt) ? n0 + 64 : n0base;
#pragma unroll
          for (int kb = 0; kb < 4; kb++) {
              int n = n0n + kb * 16 + l15; if (n > NN - 1) n = NN - 1;
              kfn[kb] = *reinterpret_cast<const short8*>(kbase + (size_t)n * CC + kg * 8);
          }
          int n = n0n + vkey; if (n > NN - 1) n = NN - 1;
          vrn = *reinterpret_cast<const short8*>(vbase + (size_t)n * CC + vd0); }

        // V^T A-fragments for this tile
        short8 va[2][2];
#pragma unroll
        for (int ks = 0; ks < 2; ks++)
#pragma unroll
            for (int dg = 0; dg < 2; dg++) {
                int row = dg * 16 + l15;
                int byteo = ((row << 7) + 64 * ks + 16 * kg) ^ ((row & 7) << 4);
                va[ks][dg] = *reinterpret_cast<const short8*>(vtb + byteo);
            }

        const bool tail = (n0 + 64 > NN);

#pragma unroll
        for (int qf = 0; qf < 5; qf++) {
            // S^T frags: row = key (16kb + 4kg + j), col = query (qf*16 + l15)
            f32x4 s[4];
#pragma unroll
            for (int kb = 0; kb < 4; kb++)
                s[kb] = MFMA16(kf[kb], qfr[qf], fz);
            if (tail) {
#pragma unroll
                for (int kb = 0; kb < 4; kb++)
#pragma unroll
                    for (int j = 0; j < 4; j++)
                        if (n0 + 16 * kb + 4 * kg + j >= NN) s[kb][j] = -1e30f;
            }
            // key-max: 16 in-register + 2 shuffles across kg groups
            float tm = fmaxf(fmaxf(s[0][0], s[0][1]), fmaxf(s[0][2], s[0][3]));
#pragma unroll
            for (int kb = 1; kb < 4; kb++)
                tm = fmaxf(tm, fmaxf(fmaxf(s[kb][0], s[kb][1]), fmaxf(s[kb][2], s[kb][3])));
            tm = fmaxf(tm, __shfl_xor(tm, 16, 64));
            tm = fmaxf(tm, __shfl_xor(tm, 32, 64));
            if (__any(tm > mrun[qf] + 8.f)) {   // defer-max (T13)
                float mn = fmaxf(mrun[qf], tm);
                float al = exp2f(mrun[qf] - mn);
                mrun[qf] = mn;
                lpart[qf] *= al;
#pragma unroll
                for (int j = 0; j < 4; j++) { o[0][qf][j] *= al; o[1][qf][j] *= al; }
            }
            // P = exp2(S - m), packed to bf16 pairs
            unsigned int pk[4][2];
            float ps = 0.f;
#pragma unroll
            for (int kb = 0; kb < 4; kb++) {
                float p0 = exp2f(s[kb][0] - mrun[qf]);
                float p1 = exp2f(s[kb][1] - mrun[qf]);
                float p2 = exp2f(s[kb][2] - mrun[qf]);
                float p3 = exp2f(s[kb][3] - mrun[qf]);
                ps += (p0 + p1) + (p2 + p3);
                pk[kb][0] = cvtpk(p0, p1);
                pk[kb][1] = cvtpk(p2, p3);
            }
            lpart[qf] += ps;
            // in-register exchange -> PV B-frags, then PV MFMAs
#pragma unroll
            for (int ks = 0; ks < 2; ks++) {
                unsigned int t0, t1, d0, d1, d2, d3;
                t0 = __shfl(pk[2 * ks][0], srcA, 64); t1 = __shfl(pk[2 * ks + 1][0], srcA, 64);
                d0 = selhi ? t1 : t0;
                t0 = __shfl(pk[2 * ks][1], srcA, 64); t1 = __shfl(pk[2 * ks + 1][1], srcA, 64);
                d1 = selhi ? t1 : t0;
                t0 = __shfl(pk[2 * ks][0], srcB, 64); t1 = __shfl(pk[2 * ks + 1][0], srcB, 64);
                d2 = selhi ? t1 : t0;
                t0 = __shfl(pk[2 * ks][1], srcB, 64); t1 = __shfl(pk[2 * ks + 1][1], srcB, 64);
                d3 = selhi ? t1 : t0;
                int4 bi; bi.x = (int)d0; bi.y = (int)d1; bi.z = (int)d2; bi.w = (int)d3;
                short8 bfr = __builtin_bit_cast(short8, bi);
                o[0][qf] = MFMA16(va[ks][0], bfr, o[0][qf]);
                o[1][qf] = MFMA16(va[ks][1], bfr, o[1][qf]);
            }
        }
#pragma unroll
        for (int kb = 0; kb < 4; kb++) kf[kb] = kfn[kb];
        vr = vrn;
    }

    // denominator: sum the 4 kg-group partials
#pragma unroll
    for (int qf = 0; qf < 5; qf++) {
        lpart[qf] += __shfl_xor(lpart[qf], 16, 64);
        lpart[qf] += __shfl_xor(lpart[qf], 32, 64);
    }

    size_t pb = (size_t)(split * 64 + bh) * QQ;
#pragma unroll
    for (int qf = 0; qf < 5; qf++) {
        int q = w * 80 + qf * 16 + l15;
        if (q >= QQ) continue;
        size_t pr = pb + q;
        if (kg == 0) { mp[pr] = mrun[qf]; lp[pr] = lpart[qf]; }
        *reinterpret_cast<f32x4*>(Op + pr * DD + kg * 4)      = o[0][qf];
        *reinterpret_cast<f32x4*>(Op + pr * DD + 16 + kg * 4) = o[1][qf];
    }
}

// ---------------- combine split partials ----------------
__global__ __launch_bounds__(256)
void comb_k(const float* __restrict__ Op, const float* __restrict__ mp,
            const float* __restrict__ lp, u16* __restrict__ ao)
{
    int g = blockIdx.x * 256 + threadIdx.x;    // 2400 rows * 8 threads
    int d4 = (g & 7) * 4;
    int row = g >> 3;
    int bh = row / QQ, qq = row - bh * QQ;
    int b = bh >> 3, h = bh & 7;
    float ms[NSPLIT], M = -1e30f;
#pragma unroll
    for (int s = 0; s < NSPLIT; s++) {
        ms[s] = mp[(size_t)(s * 64 + bh) * QQ + qq];
        M = fmaxf(M, ms[s]);
    }
    float L = 0.f, a0 = 0.f, a1 = 0.f, a2 = 0.f, a3 = 0.f;
#pragma unroll
    for (int s = 0; s < NSPLIT; s++) {
        size_t pr = (size_t)(s * 64 + bh) * QQ + qq;
        float e = exp2f(ms[s] - M);
        L += lp[pr] * e;
        float4 ov = *reinterpret_cast<const float4*>(Op + pr * DD + d4);
        a0 += e * ov.x; a1 += e * ov.y; a2 += e * ov.z; a3 += e * ov.w;
    }
    float inv = 1.0f / L;
    ushort4 u;
    u.x = f2bu(a0 * inv); u.y = f2bu(a1 * inv); u.z = f2bu(a2 * inv); u.w = f2bu(a3 * inv);
    *reinterpret_cast<ushort4*>(ao + ((size_t)(b * QQ + qq) * CC + h * DD + d4)) = u;
}

// ---------------- launch ----------------
extern "C" void kernel_launch(void* const* d_in, const int* in_sizes, int n_in,
                              void* d_out, int out_size, void* d_ws, size_t ws_size,
                              hipStream_t stream)
{
    (void)in_sizes; (void)n_in; (void)out_size; (void)ws_size;
    const float* x    = (const float*)d_in[0];
    const float* Wq   = (const float*)d_in[1];
    const float* Wk   = (const float*)d_in[2];
    const float* Wv   = (const float*)d_in[3];
    const float* Wp   = (const float*)d_in[4];
    const float* W1   = (const float*)d_in[5];
    const float* W2   = (const float*)d_in[6];
    const float* ln1w = (const float*)d_in[7];
    const float* ln1b = (const float*)d_in[8];
    const float* ln2w = (const float*)d_in[9];
    const float* ln2b = (const float*)d_in[10];
    const float* g1   = (const float*)d_in[11];
    const float* g2   = (const float*)d_in[12];
    float* out = (float*)d_out;

    char* p = (char*)d_ws;
    auto alloc = [&](size_t bytes) { char* r = p; p += (bytes + 255) & ~(size_t)255; return r; };

    const size_t MKV = (size_t)BB * NN;        // 69600
    const size_t MQ  = (size_t)BB * QQ;        // 2400

    u16* WqT  = (u16*)alloc((size_t)CC * CC * 2);
    u16* WkvT = (u16*)alloc((size_t)CC * CC * 2 * 2);   // K cols then V cols, contiguous
    u16* WpT  = (u16*)alloc((size_t)CC * CC * 2);
    u16* W1T  = (u16*)alloc((size_t)CC * HIDN * 2);
    u16* W2T  = (u16*)alloc((size_t)HIDN * CC * 2);
    u16* xn   = (u16*)alloc(MKV * CC * 2);
    u16* kbf  = (u16*)alloc(MKV * CC * 2);
    u16* vbf  = (u16*)alloc(MKV * CC * 2);
    u16* qbf  = (u16*)alloc(MQ * CC * 2);
    u16* aob  = (u16*)alloc(MQ * CC * 2);
    u16* xqb  = (u16*)alloc(MQ * CC * 2);
    u16* h1   = (u16*)alloc(MQ * HIDN * 2);
    float* pd  = (float*)alloc(MQ * CC * 4);
    float* xqf = (float*)alloc(MQ * CC * 4);
    float* Op  = (float*)alloc((size_t)NSPLIT * 64 * QQ * DD * 4);
    float* mp  = (float*)alloc((size_t)NSPLIT * 64 * QQ * 4);
    float* lp  = (float*)alloc((size_t)NSPLIT * 64 * QQ * 4);

    // D^-0.5 * log2(e): scores land in log2 domain -> exp2 everywhere
    const float qscale = 0.17677669529663687f * 1.4426950408889634f;

    wprep<<<(CC * CC + 255) / 256, 256, 0, stream>>>(Wq, WqT, CC, CC, qscale);
    wprep<<<(CC * CC + 255) / 256, 256, 0, stream>>>(Wk, WkvT, CC, CC, 1.0f);
    wprep<<<(CC * CC + 255) / 256, 256, 0, stream>>>(Wv, WkvT + (size_t)CC * CC, CC, CC, 1.0f);
    wprep<<<(CC * CC + 255) / 256, 256, 0, stream>>>(Wp, WpT, CC, CC, 1.0f);
    wprep<<<(CC * HIDN + 255) / 256, 256, 0, stream>>>(W1, W1T, CC, HIDN, 1.0f);
    wprep<<<(HIDN * CC + 255) / 256, 256, 0, stream>>>(W2, W2T, HIDN, CC, 1.0f);

    // LN1 + context output
    ln1_k<<<(int)(MKV / 4), 256, 0, stream>>>(x, ln1w, ln1b, g1, xn, out);

    // fused K+V projection (one pass over xn), then Q
    gemm_k<0><<<dim3(1088, 2), 256, 0, stream>>>(xn, WkvT, kbf, vbf, nullptr, nullptr, nullptr, nullptr,
                                                 (int)MKV, CC, CC, (int)MKV, 0);
    gemm_k<0><<<dim3(38, 1), 256, 0, stream>>>(xn, WqT, qbf, nullptr, nullptr, nullptr, nullptr, nullptr,
                                               (int)MQ, CC, CC, QQ, NN);

    // attention (key-split flash) + combine
    attn_k<<<64 * NSPLIT, 256, 0, stream>>>(qbf, kbf, vbf, Op, mp, lp);
    comb_k<<<(int)(MQ * 8 / 256), 256, 0, stream>>>(Op, mp, lp, aob);

    // proj -> f32
    gemm_k<2><<<dim3(38, 1), 256, 0, stream>>>(aob, WpT, nullptr, nullptr, pd, nullptr, nullptr, nullptr,
                                               (int)MQ, CC, CC, (int)MQ, 0);
    // residual + LN2
    ln2_k<<<(int)(MQ / 4), 256, 0, stream>>>(x, pd, g1, ln2w, ln2b, xqf, xqb);

    // MLP
    gemm_k<1><<<dim3(38, 4), 256, 0, stream>>>(xqb, W1T, h1, nullptr, nullptr, nullptr, nullptr, nullptr,
                                               (int)MQ, CC, HIDN, (int)MQ, 0);
    gemm_k<3><<<dim3(38, 1), 256, 0, stream>>>(h1, W2T, nullptr, nullptr, nullptr, xqf, g2, out,
                                               (int)MQ, HIDN, CC, (int)MQ, 0);
}